// Round 7
// baseline (394.985 us; speedup 1.0000x reference)
//
#include <hip/hip_runtime.h>
#include <hip/hip_bf16.h>
#include <stdint.h>

// Problem: B=2,T=1,C=256,H=64,W=64, K=16384 codes. argmin_k ||x_p - e_k||^2.
// R7 = R2-proven pipeline (exact layout, full-precision min1/k1/min2) + fused prep.
// R4-R6 root cause: min2 truncated to bf16 had 0.0156 slack vs 0.004 d-spread ->
// every block rescan-triggered -> 134M pairs vs 131K cap -> dropped candidates.
constexpr int C    = 256;
constexpr int HW   = 4096;
constexpr int NPIX = 8192;
constexpr int K    = 16384;

constexpr int BM = 128;     // pixels / block
constexpr int BN = 256;     // codes / block
constexpr int NB = K / BN;  // 64 code-blocks
constexpr float DELTA = 1e-4f;
constexpr unsigned PAIR_CAP = 262144;

typedef __attribute__((ext_vector_type(8))) short short8;
typedef __attribute__((ext_vector_type(4))) float f32x4;
typedef unsigned int u32;
typedef unsigned long long u64;

// ---- workspace layout (bytes) ---- byte-identical to R2's proven layout (ends 11665664)
constexpr size_t OFF_KEYS  = 0;         // u64[8192]    64K
constexpr size_t OFF_XSQ   = 65536;     // f32[8192]    32K
constexpr size_t OFF_MHAT  = 98304;     // u32[8192]    32K
constexpr size_t OFF_CNT   = 131072;    // u32 counter
constexpr size_t OFF_PAIRS = 131328;    // u32[262144]  1M
constexpr size_t OFF_MIN1  = 1179904;   // f32[8192*64] 2M
constexpr size_t OFF_K1    = 3277056;   // u32[8192*64] 2M
constexpr size_t OFF_MIN2  = 5374208;   // f32[8192*64] 2M
constexpr size_t OFF_XT    = 7471360;   // bf16[8192*256] 4M

static __device__ __forceinline__ unsigned short f2bf(float f) {
    __hip_bfloat16 h = __float2bfloat16(f);
    return *reinterpret_cast<unsigned short*>(&h);
}

// ---------- fused prep: [0,32) init+xsq | [32,544) x transpose ----------
__global__ __launch_bounds__(256) void vqprep_kernel(
    const float* __restrict__ x,
    float* __restrict__ xsq, u64* __restrict__ keys,
    unsigned* __restrict__ mhat, unsigned* __restrict__ cnt,
    unsigned short* __restrict__ xt)
{
    __shared__ float lds[64][65];
    const int bid = blockIdx.x;
    const int t   = threadIdx.x;
    if (bid < 32) {
        // exact ||x||^2 (verbatim sequential fmaf chain) + init
        const int p  = bid * 256 + t;
        const int b  = p >> 12;
        const int hw = p & 4095;
        const float* xp = x + (size_t)b * C * HW + hw;
        float acc = 0.0f;
        #pragma unroll 8
        for (int c = 0; c < C; ++c) {
            const float v = xp[(size_t)c * HW];
            acc = fmaf(v, v, acc);
        }
        xsq[p]  = acc;
        keys[p] = ~0ULL;
        mhat[p] = 0x7F7FFFFFu;   // FLT_MAX bits
        if (p == 0) *cnt = 0u;
    } else {
        // x (b,c,h,w) -> xt[p][c] bf16 via LDS transpose (R2-verbatim indexing:
        // bid2 = (b<<8)|(c0/64<<6)|(hw0/64), covering R2's grid (64,4,2) exactly)
        const int bid2 = bid - 32;
        const int hw0 = (bid2 & 63) * 64;
        const int c0  = ((bid2 >> 6) & 3) * 64;
        const int b   = bid2 >> 8;
        #pragma unroll
        for (int i = 0; i < 4; ++i) {
            const int ch  = i * 16 + (t >> 4);
            const int pix = (t & 15) * 4;
            const float4 v = *(const float4*)&x[((size_t)(b * C + c0 + ch)) * HW + hw0 + pix];
            lds[ch][pix + 0] = v.x; lds[ch][pix + 1] = v.y;
            lds[ch][pix + 2] = v.z; lds[ch][pix + 3] = v.w;
        }
        __syncthreads();
        #pragma unroll
        for (int j = 0; j < 4; ++j) {
            const int pix = j * 16 + (t >> 4);
            const int cs  = (t & 15) * 4;
            const u32 lo = (u32)f2bf(lds[cs + 0][pix]) | ((u32)f2bf(lds[cs + 1][pix]) << 16);
            const u32 hi = (u32)f2bf(lds[cs + 2][pix]) | ((u32)f2bf(lds[cs + 3][pix]) << 16);
            const int p = b * HW + hw0 + pix;
            *(uint2*)&xt[(size_t)p * C + c0 + cs] = make_uint2(lo, hi);
        }
    }
}

// ---------- pass A: bf16 MFMA GEMM (R2-verbatim) ----------
// LDS rows of 64 bf16 (128B = 8 slots of 16B); logical slot s at phys s^(row&7).
__global__ __launch_bounds__(256, 2) void vqgemm_kernel(
    const unsigned short* __restrict__ xt, const float* __restrict__ cb,
    float* __restrict__ min1a, unsigned* __restrict__ k1a, float* __restrict__ min2a,
    unsigned* __restrict__ mhat)
{
    __shared__ unsigned short a_lds[128 * 64];   // 16 KB (reused as reduce scratch)
    __shared__ unsigned short b_lds[256 * 64];   // 32 KB

    const int t    = threadIdx.x;
    const int lane = t & 63;
    const int wid  = t >> 6;          // 0..3
    const int wr   = wid >> 1;        // pixel half
    const int wc   = wid & 1;         // code half
    const int p0 = blockIdx.x * BM;
    const int n0 = blockIdx.y * BN;

    f32x4 acc[4][8];
    #pragma unroll
    for (int i = 0; i < 4; ++i)
        #pragma unroll
        for (int j = 0; j < 8; ++j) acc[i][j] = (f32x4){0.f, 0.f, 0.f, 0.f};

    for (int ks = 0; ks < 4; ++ks) {
        __syncthreads();   // previous iter's frag reads done before overwrite
        { // stage A: 128 rows x 128B from xt (bf16); 2 threads/row
            const int r = t >> 1, h = t & 1;
            const char* src = (const char*)xt + (size_t)(p0 + r) * 512 + ks * 128 + h * 64;
            #pragma unroll
            for (int j = 0; j < 4; ++j) {
                const uint4 v = *(const uint4*)(src + j * 16);
                const int s = h * 4 + j;
                *(uint4*)&a_lds[r * 64 + (s ^ (r & 7)) * 8] = v;
            }
        }
        { // stage B: fp32 -> bf16 in-register, 4 threads/row, 4 rounds
            #pragma unroll
            for (int R = 0; R < 4; ++R) {
                const int row = R * 64 + (t >> 2);
                const int seg = t & 3;
                const float* src = cb + (size_t)(n0 + row) * C + ks * 64 + seg * 16;
                u32 w[8];
                #pragma unroll
                for (int j = 0; j < 4; ++j) {
                    const float4 v = *(const float4*)(src + j * 4);
                    w[j * 2 + 0] = (u32)f2bf(v.x) | ((u32)f2bf(v.y) << 16);
                    w[j * 2 + 1] = (u32)f2bf(v.z) | ((u32)f2bf(v.w) << 16);
                }
                const int s0 = seg * 2;
                *(uint4*)&b_lds[row * 64 + ((s0 + 0) ^ (row & 7)) * 8] = make_uint4(w[0], w[1], w[2], w[3]);
                *(uint4*)&b_lds[row * 64 + ((s0 + 1) ^ (row & 7)) * 8] = make_uint4(w[4], w[5], w[6], w[7]);
            }
        }
        __syncthreads();   // tiles ready
        #pragma unroll
        for (int kk2 = 0; kk2 < 2; ++kk2) {
            short8 af[4], bfq[8];
            const int sl = kk2 * 4 + (lane >> 4);
            #pragma unroll
            for (int mf = 0; mf < 4; ++mf) {
                const int row = wr * 64 + mf * 16 + (lane & 15);
                af[mf] = *(const short8*)&a_lds[row * 64 + (sl ^ (row & 7)) * 8];
            }
            #pragma unroll
            for (int nf = 0; nf < 8; ++nf) {
                const int row = wc * 128 + nf * 16 + (lane & 15);
                bfq[nf] = *(const short8*)&b_lds[row * 64 + (sl ^ (row & 7)) * 8];
            }
            #pragma unroll
            for (int mf = 0; mf < 4; ++mf)
                #pragma unroll
                for (int nf = 0; nf < 8; ++nf)
                    acc[mf][nf] = __builtin_amdgcn_mfma_f32_16x16x32_bf16(af[mf], bfq[nf], acc[mf][nf], 0, 0, 0);
        }
    }

    __syncthreads();                    // all LDS reads done; reuse a_lds as scratch
    u32* tri = (u32*)a_lds;             // [128 pixels][2 wc][3]

    #pragma unroll
    for (int mf = 0; mf < 4; ++mf) {
        #pragma unroll
        for (int q = 0; q < 4; ++q) {
            // surrogate d = 4 - 2*dot (per-pixel shift is ranking-invariant)
            float m1 = 3.4e38f, m2 = 3.4e38f; int kl = 0;
            #pragma unroll
            for (int nf = 0; nf < 8; ++nf) {
                const float v = fmaf(-2.0f, acc[mf][nf][q], 4.0f);
                const int kk = wc * 128 + nf * 16 + (lane & 15);
                if (v < m1) { m2 = m1; m1 = v; kl = kk; }
                else        { m2 = fminf(m2, v); }
            }
            for (int s = 1; s < 16; s <<= 1) {
                const float om1 = __shfl_xor(m1, s);
                const float om2 = __shfl_xor(m2, s);
                const int   okl = __shfl_xor(kl, s);
                if (om1 < m1) { m2 = fminf(m1, om2); m1 = om1; kl = okl; }
                else          { m2 = fminf(om1, m2); }
            }
            if ((lane & 15) == 0) {
                const int pixloc = wr * 64 + mf * 16 + (lane >> 4) * 4 + q;
                const int base = (pixloc * 2 + wc) * 3;
                tri[base + 0] = __float_as_uint(m1);
                tri[base + 1] = (u32)kl;
                tri[base + 2] = __float_as_uint(m2);
            }
        }
    }
    __syncthreads();
    if (t < 128) {
        const int b0 = (t * 2 + 0) * 3, b1 = (t * 2 + 1) * 3;
        float m1 = __uint_as_float(tri[b0 + 0]); u32 kl = tri[b0 + 1];
        float m2 = __uint_as_float(tri[b0 + 2]);
        const float om1 = __uint_as_float(tri[b1 + 0]);
        const u32   okl = tri[b1 + 1];
        const float om2 = __uint_as_float(tri[b1 + 2]);
        if (om1 < m1) { m2 = fminf(m1, om2); m1 = om1; kl = okl; }
        else          { m2 = fminf(om1, m2); }
        const int p = p0 + t;
        const size_t idx = (size_t)p * NB + blockIdx.y;
        min1a[idx] = m1;                      // FULL f32 — no compression (R4-R6 lesson)
        k1a[idx]   = (u32)n0 + kl;
        min2a[idx] = m2;                      // FULL f32
        atomicMin(&mhat[p], __float_as_uint(m1));
    }
}

// ---------- pass B: flag candidate blocks -> (p,k) pair list (R2-verbatim) ----------
__global__ __launch_bounds__(256) void vqflag_kernel(
    const float* __restrict__ min1a, const unsigned* __restrict__ k1a,
    const float* __restrict__ min2a, const unsigned* __restrict__ mhat,
    unsigned* __restrict__ cnt, unsigned* __restrict__ pairs)
{
    const int idx = blockIdx.x * 256 + threadIdx.x;   // p*64 + nb
    if (idx >= NPIX * NB) return;
    const int p  = idx >> 6;
    const int nb = idx & 63;
    const float thresh = __uint_as_float(mhat[p]) + DELTA;
    if (min1a[idx] <= thresh) {
        const unsigned pos = atomicAdd(cnt, 1u);
        if (pos < PAIR_CAP) pairs[pos] = ((unsigned)p << 14) | k1a[idx];
    }
    if (min2a[idx] <= thresh) {   // >=2 near-min codes in this block: rescan all 256
        const unsigned base = atomicAdd(cnt, 256u);
        for (int j = 0; j < 256; ++j)
            if (base + j < PAIR_CAP) pairs[base + j] = ((unsigned)p << 14) | (unsigned)(nb * 256 + j);
    }
}

// ---------- pass C: exact fp32 distance (verbatim chain) for candidates ----------
__global__ __launch_bounds__(256) void vqexact_kernel(
    const float* __restrict__ x, const float* __restrict__ cb,
    const float* __restrict__ xsq, const unsigned* __restrict__ cnt,
    const unsigned* __restrict__ pairs, u64* __restrict__ keys)
{
    const unsigned n = min(*cnt, PAIR_CAP);
    for (unsigned i = blockIdx.x * 256 + threadIdx.x; i < n; i += gridDim.x * 256) {
        const unsigned pair = pairs[i];
        const int p = pair >> 14;
        const int k = pair & 16383;
        const int b = p >> 12;
        const int hw = p & 4095;
        const float* xp = x + (size_t)b * C * HW + hw;
        const float* ep = cb + (size_t)k * C;
        float acc = 0.0f;
        #pragma unroll 4
        for (int c = 0; c < C; ++c)
            acc = fmaf(xp[(size_t)c * HW], ep[c], acc);
        const float d = xsq[p] - 2.0f * acc;   // 2*acc exact => same rounding as ref
        const u64 key = ((u64)__float_as_uint(d) << 32) | (unsigned)k;
        atomicMin(&keys[p], key);
    }
}

// ---------- pass D: unpack ----------
__global__ __launch_bounds__(256) void vqout_kernel(
    const u64* __restrict__ keys, int* __restrict__ out)
{
    const int p = blockIdx.x * 256 + threadIdx.x;
    out[p] = (int)(unsigned)(keys[p] & 0xffffffffu);
}

extern "C" void kernel_launch(void* const* d_in, const int* in_sizes, int n_in,
                              void* d_out, int out_size, void* d_ws, size_t ws_size,
                              hipStream_t stream)
{
    const float* x  = (const float*)d_in[0];
    const float* cb = (const float*)d_in[1];
    int* out = (int*)d_out;
    char* ws = (char*)d_ws;

    u64*      keys  = (u64*)(ws + OFF_KEYS);
    float*    xsq   = (float*)(ws + OFF_XSQ);
    unsigned* mhat  = (unsigned*)(ws + OFF_MHAT);
    unsigned* cnt   = (unsigned*)(ws + OFF_CNT);
    unsigned* pairs = (unsigned*)(ws + OFF_PAIRS);
    float*    min1a = (float*)(ws + OFF_MIN1);
    unsigned* k1a   = (unsigned*)(ws + OFF_K1);
    float*    min2a = (float*)(ws + OFF_MIN2);
    unsigned short* xt = (unsigned short*)(ws + OFF_XT);

    vqprep_kernel<<<544, 256, 0, stream>>>(x, xsq, keys, mhat, cnt, xt);
    vqgemm_kernel<<<dim3(NPIX / BM, K / BN), 256, 0, stream>>>(xt, cb, min1a, k1a, min2a, mhat);
    vqflag_kernel<<<(NPIX * NB) / 256, 256, 0, stream>>>(min1a, k1a, min2a, mhat, cnt, pairs);
    vqexact_kernel<<<1024, 256, 0, stream>>>(x, cb, xsq, cnt, pairs, keys);
    vqout_kernel<<<NPIX / 256, 256, 0, stream>>>(keys, out);
}